// Round 4
// baseline (1128.153 us; speedup 1.0000x reference)
//
#include <hip/hip_runtime.h>
#include <hip/hip_bf16.h>
#include <cstdint>

#define BB 128
#define LL 28
#define FF 28
#define DM 256
#define DI 512
#define DS 16
#define DR 16
#define KK 3
#define NLAYER 5
#define NOUT 10
#define NTOK (BB * LL)      // 3584
#define NDBC (DR + 2 * DS)  // 48
#define CPB 16              // channels per scan block

__device__ __forceinline__ float sigmoidf_(float x) { return 1.0f / (1.0f + __expf(-x)); }
__device__ __forceinline__ float siluf_(float x) { return x * sigmoidf_(x); }
__device__ __forceinline__ float softplusf_(float x) {
    return (x > 20.0f) ? x : log1pf(expf(x));
}

// C[M,N] = epilogue( A[M,lda] @ W[N,K]^T )
// Tiles: BM=16*TM, BN=16*TN, BK=16. 256 threads as 16x16; each thread owns a
// contiguous TM x TN output sub-tile.
// EPI 0: C = AB      EPI 2: C += AB (residual, in-place)
template <int TM, int TN, int EPI>
__global__ __launch_bounds__(256) void gemm_nt(const float* __restrict__ A, int lda,
                                               const float* __restrict__ W,
                                               float* __restrict__ C,
                                               int M, int N, int K) {
    constexpr int BM = 16 * TM;
    constexpr int BN = 16 * TN;
    __shared__ float As[16][BM + 4];
    __shared__ float Ws[16][BN + 4];

    const int tid = threadIdx.x;
    const int kk = tid & 15;
    const int row = tid >> 4;
    const int tx = tid & 15;
    const int ty = tid >> 4;
    const int bm = blockIdx.y * BM;
    const int bn = blockIdx.x * BN;

    float acc[TM][TN];
    #pragma unroll
    for (int i = 0; i < TM; ++i)
        #pragma unroll
        for (int j = 0; j < TN; ++j) acc[i][j] = 0.f;

    for (int k0 = 0; k0 < K; k0 += 16) {
        const int k = k0 + kk;
        const bool kok = (k < K);
        #pragma unroll
        for (int r = 0; r < TM; ++r) {
            int m = bm + r * 16 + row;
            As[kk][r * 16 + row] = kok ? A[(size_t)m * lda + k] : 0.f;
        }
        #pragma unroll
        for (int r = 0; r < TN; ++r) {
            int n = bn + r * 16 + row;
            Ws[kk][r * 16 + row] = kok ? W[(size_t)n * K + k] : 0.f;
        }
        __syncthreads();
        #pragma unroll
        for (int k2 = 0; k2 < 16; ++k2) {
            float a[TM], b[TN];
            #pragma unroll
            for (int i = 0; i < TM; ++i) a[i] = As[k2][ty * TM + i];
            #pragma unroll
            for (int j = 0; j < TN; ++j) b[j] = Ws[k2][tx * TN + j];
            #pragma unroll
            for (int i = 0; i < TM; ++i)
                #pragma unroll
                for (int j = 0; j < TN; ++j) acc[i][j] += a[i] * b[j];
        }
        __syncthreads();
    }

    #pragma unroll
    for (int i = 0; i < TM; ++i) {
        const int m = bm + ty * TM + i;
        #pragma unroll
        for (int j = 0; j < TN; ++j) {
            const int n = bn + tx * TN + j;
            float v = acc[i][j];
            if (EPI == 2) v += C[(size_t)m * N + n];
            C[(size_t)m * N + n] = v;
        }
    }
}

// u[m, di] = silu( causal_depthwise_conv3(xb)[m,di] + cb[di] ),  xb = xz[:, :DI]
__global__ void conv_silu_kernel(const float* __restrict__ xz,
                                 const float* __restrict__ cw,   // [DI, K]
                                 const float* __restrict__ cb,   // [DI]
                                 float* __restrict__ u) {
    int idx = blockIdx.x * 256 + threadIdx.x;
    if (idx >= NTOK * DI) return;
    int di = idx & (DI - 1);
    int m = idx >> 9;
    int l = m % LL;
    int b = m / LL;
    float acc = cb[di];
    #pragma unroll
    for (int k = 0; k < KK; ++k) {
        int lsrc = l + k - (KK - 1);
        if (lsrc >= 0) {
            acc += xz[(size_t)(b * LL + lsrc) * (2 * DI) + di] * cw[di * KK + k];
        }
    }
    u[(size_t)m * DI + di] = siluf_(acc);
}

// Selective scan, state-parallel: thread = (batch, channel, state).
// Block = 256 threads = 16 channels x 16 states. Grid = (BB, DI/16) = 4096.
// Recurrence state is ONE register per thread; dt-projection and C-readout
// are 16-lane shfl_xor butterfly reductions. No barriers in the 28-step loop.
__global__ __launch_bounds__(256) void scan_kernel(
                            const float* __restrict__ u,     // [NTOK, DI]
                            const float* __restrict__ dbc,   // [NTOK, NDBC]
                            const float* __restrict__ xz,    // [NTOK, 2*DI]
                            const float* __restrict__ dtw,   // [DI, DR]
                            const float* __restrict__ dtb,   // [DI]
                            const float* __restrict__ A_log, // [DI, DS]
                            const float* __restrict__ Dv,    // [DI]
                            float* __restrict__ y) {         // [NTOK, DI]
    const int b = blockIdx.x;
    const int di0 = blockIdx.y * CPB;
    const int t = threadIdx.x;
    const int g = t >> 4;    // channel within block
    const int s = t & 15;    // state index
    const int di = di0 + g;

    __shared__ float sdbc[LL][NDBC];  // 5.25 KB: dt | B | C rows for this batch
    __shared__ float su[LL][CPB];     // 1.75 KB: u for this channel slab
    __shared__ float sy[LL][CPB];     // 1.75 KB: scan outputs

    // one-shot cooperative staging (coalesced)
    {
        const float* src = dbc + (size_t)b * LL * NDBC;
        for (int i = t; i < LL * NDBC; i += 256) sdbc[i / NDBC][i % NDBC] = src[i];
        for (int i = t; i < LL * CPB; i += 256) {
            int l = i >> 4, c = i & 15;
            su[l][c] = u[(size_t)(b * LL + l) * DI + di0 + c];
        }
    }

    const float wdt   = dtw[(size_t)di * DR + s];        // coalesced
    const float A     = -expf(A_log[(size_t)di * DS + s]); // coalesced
    const float dbias = dtb[di];

    __syncthreads();

    float st = 0.f;
    #pragma unroll
    for (int l = 0; l < LL; ++l) {
        // delta = softplus(dt-row . dtw[di] + dtb[di]) via 16-lane reduce
        float dtv = wdt * sdbc[l][s];
        dtv += __shfl_xor(dtv, 1);
        dtv += __shfl_xor(dtv, 2);
        dtv += __shfl_xor(dtv, 4);
        dtv += __shfl_xor(dtv, 8);
        const float d = softplusf_(dtv + dbias);

        const float uu = su[l][g];
        st = __expf(d * A) * st + (d * uu) * sdbc[l][DR + s];

        float p = st * sdbc[l][DR + DS + s];
        p += __shfl_xor(p, 1);
        p += __shfl_xor(p, 2);
        p += __shfl_xor(p, 4);
        p += __shfl_xor(p, 8);
        if (s == 0) sy[l][g] = p;
    }
    __syncthreads();

    // epilogue: y = (scan_y + u*D) * silu(z), coalesced 16-float chunks
    for (int i = t; i < LL * CPB; i += 256) {
        int l = i >> 4, c = i & 15;
        const int m = b * LL + l;
        const float uu = su[l][c];
        const float zz = xz[(size_t)m * (2 * DI) + DI + di0 + c];
        const float Dc = Dv[di0 + c];
        y[(size_t)m * DI + di0 + c] = (sy[l][c] + uu * Dc) * siluf_(zz);
    }
}

__global__ void pool_classifier_kernel(const float* __restrict__ h,   // [NTOK, DM]
                                       const float* __restrict__ cls, // [NOUT, DM]
                                       float* __restrict__ out) {     // [BB, NOUT]
    const int b = blockIdx.x;
    const int dm = threadIdx.x;
    __shared__ float pool[DM];
    float p = 0.f;
    for (int l = 0; l < LL; ++l) p += h[(size_t)(b * LL + l) * DM + dm];
    pool[dm] = p * (1.0f / LL);
    __syncthreads();
    if (dm < NOUT) {
        float acc = 0.f;
        for (int k = 0; k < DM; ++k) acc += pool[k] * cls[dm * DM + k];
        out[b * NOUT + dm] = acc;
    }
}

extern "C" void kernel_launch(void* const* d_in, const int* in_sizes, int n_in,
                              void* d_out, int out_size, void* d_ws, size_t ws_size,
                              hipStream_t stream) {
    const float* x       = (const float*)d_in[0];
    const float* ipw     = (const float*)d_in[1];
    const float* inw     = (const float*)d_in[2];
    const float* convw   = (const float*)d_in[3];
    const float* convb   = (const float*)d_in[4];
    const float* xpw     = (const float*)d_in[5];
    const float* dtw     = (const float*)d_in[6];
    const float* dtb     = (const float*)d_in[7];
    const float* alog    = (const float*)d_in[8];
    const float* Dvec    = (const float*)d_in[9];
    const float* opw     = (const float*)d_in[10];
    const float* clsw    = (const float*)d_in[11];
    float* out = (float*)d_out;

    float* ws = (float*)d_ws;
    float* h   = ws;                              // NTOK*DM
    float* xz  = h + (size_t)NTOK * DM;           // NTOK*2*DI
    float* u   = xz + (size_t)NTOK * 2 * DI;      // NTOK*DI
    float* dbc = u + (size_t)NTOK * DI;           // NTOK*48
    float* y   = dbc + (size_t)NTOK * NDBC;       // NTOK*DI

    dim3 blk(256);

    // input projection: h = x @ ipw^T   (M=3584, N=256, K=28)
    hipLaunchKernelGGL((gemm_nt<4, 4, 0>), dim3(DM / 64, NTOK / 64), blk, 0, stream,
                       x, FF, ipw, h, NTOK, DM, FF);

    for (int layer = 0; layer < NLAYER; ++layer) {
        const float* inw_l   = inw  + (size_t)layer * 2 * DI * DM;
        const float* convw_l = convw + (size_t)layer * DI * KK;
        const float* convb_l = convb + (size_t)layer * DI;
        const float* xpw_l   = xpw  + (size_t)layer * NDBC * DI;
        const float* dtw_l   = dtw  + (size_t)layer * DI * DR;
        const float* dtb_l   = dtb  + (size_t)layer * DI;
        const float* alog_l  = alog + (size_t)layer * DI * DS;
        const float* Dvec_l  = Dvec + (size_t)layer * DI;
        const float* opw_l   = opw  + (size_t)layer * DM * DI;

        // xz = h @ inw^T   (M=3584, N=1024, K=256): 64x64 tiles
        hipLaunchKernelGGL((gemm_nt<4, 4, 0>), dim3(2 * DI / 64, NTOK / 64), blk, 0, stream,
                           h, DM, inw_l, xz, NTOK, 2 * DI, DM);

        // u = silu(conv(xb) + cb)
        hipLaunchKernelGGL(conv_silu_kernel, dim3((NTOK * DI) / 256), blk, 0, stream,
                           xz, convw_l, convb_l, u);

        // dbc = u @ xpw^T   (M=3584, N=48, K=512): 32x48 tiles
        hipLaunchKernelGGL((gemm_nt<2, 3, 0>), dim3(1, NTOK / 32), blk, 0, stream,
                           u, DI, xpw_l, dbc, NTOK, NDBC, DI);

        // selective scan (state-parallel, fused dt_proj + gating)
        hipLaunchKernelGGL(scan_kernel, dim3(BB, DI / CPB), blk, 0, stream,
                           u, dbc, xz, dtw_l, dtb_l, alog_l, Dvec_l, y);

        // h += y @ opw^T   (M=3584, N=256, K=512): 64x32 tiles
        hipLaunchKernelGGL((gemm_nt<4, 2, 2>), dim3(DM / 32, NTOK / 64), blk, 0, stream,
                           y, DI, opw_l, h, NTOK, DM, DI);
    }

    hipLaunchKernelGGL(pool_classifier_kernel, dim3(BB), dim3(DM), 0, stream,
                       h, clsw, out);
}

// Round 5
// 788.152 us; speedup vs baseline: 1.4314x; 1.4314x over previous
//
#include <hip/hip_runtime.h>
#include <hip/hip_bf16.h>
#include <cstdint>

#define BB 128
#define LL 28
#define FF 28
#define DM 256
#define DI 512
#define DS 16
#define DR 16
#define KK 3
#define NLAYER 5
#define NOUT 10
#define NTOK (BB * LL)      // 3584
#define NDBC (DR + 2 * DS)  // 48
#define SCPB 64             // channels per scan block (= 1 wave)

__device__ __forceinline__ float sigmoidf_(float x) { return 1.0f / (1.0f + __expf(-x)); }
__device__ __forceinline__ float siluf_(float x) { return x * sigmoidf_(x); }
__device__ __forceinline__ float softplusf_(float x) {
    return (x > 20.0f) ? x : log1pf(expf(x));
}

// C[M,N] = epilogue( A[M,lda] @ W[N,K]^T )
// EPI 0: C = AB      EPI 2: C += AB (residual, in-place)
template <int TM, int TN, int EPI>
__global__ __launch_bounds__(256) void gemm_nt(const float* __restrict__ A, int lda,
                                               const float* __restrict__ W,
                                               float* __restrict__ C,
                                               int M, int N, int K) {
    constexpr int BM = 16 * TM;
    constexpr int BN = 16 * TN;
    __shared__ float As[16][BM + 4];
    __shared__ float Ws[16][BN + 4];

    const int tid = threadIdx.x;
    const int kk = tid & 15;
    const int row = tid >> 4;
    const int tx = tid & 15;
    const int ty = tid >> 4;
    const int bm = blockIdx.y * BM;
    const int bn = blockIdx.x * BN;

    float acc[TM][TN];
    #pragma unroll
    for (int i = 0; i < TM; ++i)
        #pragma unroll
        for (int j = 0; j < TN; ++j) acc[i][j] = 0.f;

    for (int k0 = 0; k0 < K; k0 += 16) {
        const int k = k0 + kk;
        const bool kok = (k < K);
        #pragma unroll
        for (int r = 0; r < TM; ++r) {
            int m = bm + r * 16 + row;
            As[kk][r * 16 + row] = kok ? A[(size_t)m * lda + k] : 0.f;
        }
        #pragma unroll
        for (int r = 0; r < TN; ++r) {
            int n = bn + r * 16 + row;
            Ws[kk][r * 16 + row] = kok ? W[(size_t)n * K + k] : 0.f;
        }
        __syncthreads();
        #pragma unroll
        for (int k2 = 0; k2 < 16; ++k2) {
            float a[TM], b[TN];
            #pragma unroll
            for (int i = 0; i < TM; ++i) a[i] = As[k2][ty * TM + i];
            #pragma unroll
            for (int j = 0; j < TN; ++j) b[j] = Ws[k2][tx * TN + j];
            #pragma unroll
            for (int i = 0; i < TM; ++i)
                #pragma unroll
                for (int j = 0; j < TN; ++j) acc[i][j] += a[i] * b[j];
        }
        __syncthreads();
    }

    #pragma unroll
    for (int i = 0; i < TM; ++i) {
        const int m = bm + ty * TM + i;
        #pragma unroll
        for (int j = 0; j < TN; ++j) {
            const int n = bn + tx * TN + j;
            float v = acc[i][j];
            if (EPI == 2) v += C[(size_t)m * N + n];
            C[(size_t)m * N + n] = v;
        }
    }
}

// u[m, di] = silu( causal_depthwise_conv3(xb)[m,di] + cb[di] ),  xb = xz[:, :DI]
__global__ void conv_silu_kernel(const float* __restrict__ xz,
                                 const float* __restrict__ cw,   // [DI, K]
                                 const float* __restrict__ cb,   // [DI]
                                 float* __restrict__ u) {
    int idx = blockIdx.x * 256 + threadIdx.x;
    if (idx >= NTOK * DI) return;
    int di = idx & (DI - 1);
    int m = idx >> 9;
    int l = m % LL;
    int b = m / LL;
    float acc = cb[di];
    #pragma unroll
    for (int k = 0; k < KK; ++k) {
        int lsrc = l + k - (KK - 1);
        if (lsrc >= 0) {
            acc += xz[(size_t)(b * LL + lsrc) * (2 * DI) + di] * cw[di * KK + k];
        }
    }
    u[(size_t)m * DI + di] = siluf_(acc);
}

// Selective scan, thread-per-channel, all operands LDS-resident.
// Block = 64 threads (1 wave) = 64 channels of one batch. Grid = (BB, DI/64).
// One barrier total; 28-step loop does LDS broadcasts + register math only.
// State lives in 16 statically-indexed registers (1-FMA chain per step).
__global__ __launch_bounds__(64) void scan_kernel(
                            const float* __restrict__ u,     // [NTOK, DI]
                            const float* __restrict__ dbc,   // [NTOK, NDBC]
                            const float* __restrict__ xz,    // [NTOK, 2*DI]
                            const float* __restrict__ dtw,   // [DI, DR]
                            const float* __restrict__ dtb,   // [DI]
                            const float* __restrict__ A_log, // [DI, DS]
                            const float* __restrict__ Dv,    // [DI]
                            float* __restrict__ y) {         // [NTOK, DI]
    const int b = blockIdx.x;
    const int di0 = blockIdx.y * SCPB;
    const int t = threadIdx.x;      // 0..63
    const int di = di0 + t;

    __shared__ float sdbc[LL][NDBC];   // 5.25 KB  dt|B|C rows of this batch
    __shared__ float su[LL][SCPB];     // 7 KB     u slab
    __shared__ float sz[LL][SCPB];     // 7 KB     z slab

    // ---- prologue: float4 cooperative staging, then ONE barrier ----
    {
        const float4* s4 = (const float4*)(dbc + (size_t)b * LL * NDBC);
        float4* d4 = (float4*)&sdbc[0][0];
        for (int i = t; i < LL * NDBC / 4; i += 64) d4[i] = s4[i];   // 336 vec4
        for (int i = t; i < LL * (SCPB / 4); i += 64) {              // 448 vec4
            const int l = i >> 4, c = i & 15;
            ((float4*)&su[l][0])[c] =
                ((const float4*)(u + (size_t)(b * LL + l) * DI + di0))[c];
            ((float4*)&sz[l][0])[c] =
                ((const float4*)(xz + (size_t)(b * LL + l) * 2 * DI + DI + di0))[c];
        }
    }

    // per-channel constants (each thread: 16+16 consecutive floats, float4)
    float wdt[DR], A[DS];
    {
        const float4* w4 = (const float4*)(dtw + (size_t)di * DR);
        #pragma unroll
        for (int q = 0; q < DR / 4; ++q) {
            float4 v = w4[q];
            wdt[q * 4 + 0] = v.x; wdt[q * 4 + 1] = v.y;
            wdt[q * 4 + 2] = v.z; wdt[q * 4 + 3] = v.w;
        }
        const float4* a4 = (const float4*)(A_log + (size_t)di * DS);
        #pragma unroll
        for (int q = 0; q < DS / 4; ++q) {
            float4 v = a4[q];
            A[q * 4 + 0] = -expf(v.x); A[q * 4 + 1] = -expf(v.y);
            A[q * 4 + 2] = -expf(v.z); A[q * 4 + 3] = -expf(v.w);
        }
    }
    const float dbias = dtb[di];
    const float Dd = Dv[di];

    __syncthreads();

    float st_[DS];
    #pragma unroll
    for (int s = 0; s < DS; ++s) st_[s] = 0.f;

    #pragma unroll 4
    for (int l = 0; l < LL; ++l) {
        float dtv = dbias;
        #pragma unroll
        for (int r = 0; r < DR; ++r) dtv += wdt[r] * sdbc[l][r];
        const float d = softplusf_(dtv);

        const float uu = su[l][t];
        const float du = d * uu;
        float yv = 0.f;
        #pragma unroll
        for (int s = 0; s < DS; ++s) {
            st_[s] = __expf(d * A[s]) * st_[s] + du * sdbc[l][DR + s];
            yv += st_[s] * sdbc[l][DR + DS + s];
        }
        y[(size_t)(b * LL + l) * DI + di] = (yv + uu * Dd) * siluf_(sz[l][t]);
    }
}

__global__ void pool_classifier_kernel(const float* __restrict__ h,   // [NTOK, DM]
                                       const float* __restrict__ cls, // [NOUT, DM]
                                       float* __restrict__ out) {     // [BB, NOUT]
    const int b = blockIdx.x;
    const int dm = threadIdx.x;
    __shared__ float pool[DM];
    float p = 0.f;
    for (int l = 0; l < LL; ++l) p += h[(size_t)(b * LL + l) * DM + dm];
    pool[dm] = p * (1.0f / LL);
    __syncthreads();
    if (dm < NOUT) {
        float acc = 0.f;
        for (int k = 0; k < DM; ++k) acc += pool[k] * cls[dm * DM + k];
        out[b * NOUT + dm] = acc;
    }
}

extern "C" void kernel_launch(void* const* d_in, const int* in_sizes, int n_in,
                              void* d_out, int out_size, void* d_ws, size_t ws_size,
                              hipStream_t stream) {
    const float* x       = (const float*)d_in[0];
    const float* ipw     = (const float*)d_in[1];
    const float* inw     = (const float*)d_in[2];
    const float* convw   = (const float*)d_in[3];
    const float* convb   = (const float*)d_in[4];
    const float* xpw     = (const float*)d_in[5];
    const float* dtw     = (const float*)d_in[6];
    const float* dtb     = (const float*)d_in[7];
    const float* alog    = (const float*)d_in[8];
    const float* Dvec    = (const float*)d_in[9];
    const float* opw     = (const float*)d_in[10];
    const float* clsw    = (const float*)d_in[11];
    float* out = (float*)d_out;

    float* ws = (float*)d_ws;
    float* h   = ws;                              // NTOK*DM
    float* xz  = h + (size_t)NTOK * DM;           // NTOK*2*DI
    float* u   = xz + (size_t)NTOK * 2 * DI;      // NTOK*DI
    float* dbc = u + (size_t)NTOK * DI;           // NTOK*48
    float* y   = dbc + (size_t)NTOK * NDBC;       // NTOK*DI

    dim3 blk(256);

    // input projection: h = x @ ipw^T   (M=3584, N=256, K=28)
    hipLaunchKernelGGL((gemm_nt<4, 4, 0>), dim3(DM / 64, NTOK / 64), blk, 0, stream,
                       x, FF, ipw, h, NTOK, DM, FF);

    for (int layer = 0; layer < NLAYER; ++layer) {
        const float* inw_l   = inw  + (size_t)layer * 2 * DI * DM;
        const float* convw_l = convw + (size_t)layer * DI * KK;
        const float* convb_l = convb + (size_t)layer * DI;
        const float* xpw_l   = xpw  + (size_t)layer * NDBC * DI;
        const float* dtw_l   = dtw  + (size_t)layer * DI * DR;
        const float* dtb_l   = dtb  + (size_t)layer * DI;
        const float* alog_l  = alog + (size_t)layer * DI * DS;
        const float* Dvec_l  = Dvec + (size_t)layer * DI;
        const float* opw_l   = opw  + (size_t)layer * DM * DI;

        // xz = h @ inw^T   (M=3584, N=1024, K=256): 64x64 tiles
        hipLaunchKernelGGL((gemm_nt<4, 4, 0>), dim3(2 * DI / 64, NTOK / 64), blk, 0, stream,
                           h, DM, inw_l, xz, NTOK, 2 * DI, DM);

        // u = silu(conv(xb) + cb)
        hipLaunchKernelGGL(conv_silu_kernel, dim3((NTOK * DI) / 256), blk, 0, stream,
                           xz, convw_l, convb_l, u);

        // dbc = u @ xpw^T   (M=3584, N=48, K=512): 32x48 tiles
        hipLaunchKernelGGL((gemm_nt<2, 3, 0>), dim3(1, NTOK / 32), blk, 0, stream,
                           u, DI, xpw_l, dbc, NTOK, NDBC, DI);

        // selective scan (thread-per-channel, LDS-resident operands)
        hipLaunchKernelGGL(scan_kernel, dim3(BB, DI / SCPB), dim3(SCPB), 0, stream,
                           u, dbc, xz, dtw_l, dtb_l, alog_l, Dvec_l, y);

        // h += y @ opw^T   (M=3584, N=256, K=512): 64x32 tiles
        hipLaunchKernelGGL((gemm_nt<4, 2, 2>), dim3(DM / 32, NTOK / 64), blk, 0, stream,
                           y, DI, opw_l, h, NTOK, DM, DI);
    }

    hipLaunchKernelGGL(pool_classifier_kernel, dim3(BB), dim3(DM), 0, stream,
                       h, clsw, out);
}

// Round 6
// 400.029 us; speedup vs baseline: 2.8202x; 1.9702x over previous
//
#include <hip/hip_runtime.h>
#include <hip/hip_bf16.h>
#include <cstdint>

#define BB 128
#define LL 28
#define FF 28
#define DM 256
#define DI 512
#define DS 16
#define DR 16
#define KK 3
#define NLAYER 5
#define NOUT 10
#define NTOK (BB * LL)      // 3584
#define NDBC (DR + 2 * DS)  // 48
#define SCPB 64             // channels per scan block (= 1 wave)

typedef __attribute__((ext_vector_type(8))) short bf16x8;
typedef __attribute__((ext_vector_type(4))) float f32x4;

__device__ __forceinline__ float sigmoidf_(float x) { return 1.0f / (1.0f + __expf(-x)); }
__device__ __forceinline__ float siluf_(float x) { return x * sigmoidf_(x); }
__device__ __forceinline__ float softplusf_(float x) {
    return (x > 20.0f) ? x : log1pf(expf(x));
}

// ---------------- fp32 tiled GEMM (input projection only, K=28) ----------------
template <int TM, int TN, int EPI>
__global__ __launch_bounds__(256) void gemm_nt(const float* __restrict__ A, int lda,
                                               const float* __restrict__ W,
                                               float* __restrict__ C,
                                               int M, int N, int K) {
    constexpr int BM = 16 * TM;
    constexpr int BN = 16 * TN;
    __shared__ float As[16][BM + 4];
    __shared__ float Ws[16][BN + 4];

    const int tid = threadIdx.x;
    const int kk = tid & 15;
    const int row = tid >> 4;
    const int tx = tid & 15;
    const int ty = tid >> 4;
    const int bm = blockIdx.y * BM;
    const int bn = blockIdx.x * BN;

    float acc[TM][TN];
    #pragma unroll
    for (int i = 0; i < TM; ++i)
        #pragma unroll
        for (int j = 0; j < TN; ++j) acc[i][j] = 0.f;

    for (int k0 = 0; k0 < K; k0 += 16) {
        const int k = k0 + kk;
        const bool kok = (k < K);
        #pragma unroll
        for (int r = 0; r < TM; ++r) {
            int m = bm + r * 16 + row;
            As[kk][r * 16 + row] = kok ? A[(size_t)m * lda + k] : 0.f;
        }
        #pragma unroll
        for (int r = 0; r < TN; ++r) {
            int n = bn + r * 16 + row;
            Ws[kk][r * 16 + row] = kok ? W[(size_t)n * K + k] : 0.f;
        }
        __syncthreads();
        #pragma unroll
        for (int k2 = 0; k2 < 16; ++k2) {
            float a[TM], b[TN];
            #pragma unroll
            for (int i = 0; i < TM; ++i) a[i] = As[k2][ty * TM + i];
            #pragma unroll
            for (int j = 0; j < TN; ++j) b[j] = Ws[k2][tx * TN + j];
            #pragma unroll
            for (int i = 0; i < TM; ++i)
                #pragma unroll
                for (int j = 0; j < TN; ++j) acc[i][j] += a[i] * b[j];
        }
        __syncthreads();
    }

    #pragma unroll
    for (int i = 0; i < TM; ++i) {
        const int m = bm + ty * TM + i;
        #pragma unroll
        for (int j = 0; j < TN; ++j) {
            const int n = bn + tx * TN + j;
            float v = acc[i][j];
            if (EPI == 2) v += C[(size_t)m * N + n];
            C[(size_t)m * N + n] = v;
        }
    }
}

// ---------------- bf16 MFMA GEMM: C[M,N] (+)= A[M,K] @ W[N,K]^T ----------------
// Both A and W are K-major (stride-1 in K) -> identical fragment addressing for
// A and B operands; the MFMA k-slot permutation cancels. C/D layout per m89:
// col = lane&15, row = (lane>>4)*4 + reg.
// EPI 0: C = acc (fp32).  EPI 2: C += acc, and Cb = bf16(C_new) mirror.
template <int BM, int BN, int WAVES_M, int WAVES_N, int EPI>
__global__ __launch_bounds__(256) void gemm_mfma_nt(
        const __hip_bfloat16* __restrict__ A, int lda,
        const __hip_bfloat16* __restrict__ W,   // [N][K]
        float* __restrict__ C,
        __hip_bfloat16* __restrict__ Cb,
        int M, int N, int K) {
    constexpr int BK = 32;
    constexpr int LDT = BK + 8;     // +8 bf16 pad -> 80B row stride, 2-way max
    constexpr int WTM = BM / WAVES_M;
    constexpr int WTN = BN / WAVES_N;
    constexpr int FM = WTM / 16;
    constexpr int FN = WTN / 16;

    __shared__ __align__(16) __hip_bfloat16 As[BM][LDT];
    __shared__ __align__(16) __hip_bfloat16 Ws[BN][LDT];

    const int tid = threadIdx.x;
    const int wave = tid >> 6;
    const int lane = tid & 63;
    const int wr = wave / WAVES_N;
    const int wc = wave % WAVES_N;
    const int bm = blockIdx.y * BM;
    const int bn = blockIdx.x * BN;

    const int r4 = tid >> 2;          // 0..63  (staging row)
    const int c8 = (tid & 3) * 8;     // 0,8,16,24 (staging k offset)

    f32x4 acc[FM][FN] = {};

    const int koff = (lane >> 4) * 8;
    const int rla = lane & 15;

    for (int k0 = 0; k0 < K; k0 += BK) {
        for (int rr = r4; rr < BM; rr += 64)
            *(int4*)&As[rr][c8] = *(const int4*)&A[(size_t)(bm + rr) * lda + k0 + c8];
        for (int rr = r4; rr < BN; rr += 64)
            *(int4*)&Ws[rr][c8] = *(const int4*)&W[(size_t)(bn + rr) * K + k0 + c8];
        __syncthreads();

        bf16x8 af[FM], wf[FN];
        #pragma unroll
        for (int i = 0; i < FM; ++i)
            af[i] = *(const bf16x8*)&As[wr * WTM + i * 16 + rla][koff];
        #pragma unroll
        for (int j = 0; j < FN; ++j)
            wf[j] = *(const bf16x8*)&Ws[wc * WTN + j * 16 + rla][koff];
        #pragma unroll
        for (int i = 0; i < FM; ++i)
            #pragma unroll
            for (int j = 0; j < FN; ++j)
                acc[i][j] = __builtin_amdgcn_mfma_f32_16x16x32_bf16(af[i], wf[j], acc[i][j], 0, 0, 0);
        __syncthreads();
    }

    const int lrow = (lane >> 4) * 4;
    const int lcol = lane & 15;
    #pragma unroll
    for (int i = 0; i < FM; ++i) {
        #pragma unroll
        for (int j = 0; j < FN; ++j) {
            #pragma unroll
            for (int r = 0; r < 4; ++r) {
                const int m = bm + wr * WTM + i * 16 + lrow + r;
                const int n = bn + wc * WTN + j * 16 + lcol;
                float v = acc[i][j][r];
                if (EPI == 2) {
                    v += C[(size_t)m * N + n];
                    C[(size_t)m * N + n] = v;
                    Cb[(size_t)m * N + n] = __float2bfloat16(v);
                } else {
                    C[(size_t)m * N + n] = v;
                }
            }
        }
    }
}

// ---------------- elementwise cast fp32 -> bf16 (n divisible by 4) ----------------
__global__ void cast_f32_bf16(const float* __restrict__ s, __hip_bfloat16* __restrict__ d, int n) {
    int i = (blockIdx.x * 256 + threadIdx.x) * 4;
    if (i >= n) return;
    float4 v = *(const float4*)&s[i];
    d[i + 0] = __float2bfloat16(v.x);
    d[i + 1] = __float2bfloat16(v.y);
    d[i + 2] = __float2bfloat16(v.z);
    d[i + 3] = __float2bfloat16(v.w);
}

// u = silu(conv(xb)+cb), written fp32 (for scan) and bf16 (for x_proj GEMM)
__global__ void conv_silu_kernel(const float* __restrict__ xz,
                                 const float* __restrict__ cw,   // [DI, K]
                                 const float* __restrict__ cb,   // [DI]
                                 float* __restrict__ u,
                                 __hip_bfloat16* __restrict__ ub) {
    int idx = blockIdx.x * 256 + threadIdx.x;
    if (idx >= NTOK * DI) return;
    int di = idx & (DI - 1);
    int m = idx >> 9;
    int l = m % LL;
    int b = m / LL;
    float acc = cb[di];
    #pragma unroll
    for (int k = 0; k < KK; ++k) {
        int lsrc = l + k - (KK - 1);
        if (lsrc >= 0) {
            acc += xz[(size_t)(b * LL + lsrc) * (2 * DI) + di] * cw[di * KK + k];
        }
    }
    float v = siluf_(acc);
    u[(size_t)m * DI + di] = v;
    ub[(size_t)m * DI + di] = __float2bfloat16(v);
}

// Selective scan, thread-per-channel, LDS-resident operands; writes y as bf16
// (consumed only by the out_proj MFMA GEMM).
__global__ __launch_bounds__(64) void scan_kernel(
                            const float* __restrict__ u,     // [NTOK, DI]
                            const float* __restrict__ dbc,   // [NTOK, NDBC]
                            const float* __restrict__ xz,    // [NTOK, 2*DI]
                            const float* __restrict__ dtw,   // [DI, DR]
                            const float* __restrict__ dtb,   // [DI]
                            const float* __restrict__ A_log, // [DI, DS]
                            const float* __restrict__ Dv,    // [DI]
                            __hip_bfloat16* __restrict__ yb) { // [NTOK, DI]
    const int b = blockIdx.x;
    const int di0 = blockIdx.y * SCPB;
    const int t = threadIdx.x;      // 0..63
    const int di = di0 + t;

    __shared__ float sdbc[LL][NDBC];
    __shared__ float su[LL][SCPB];
    __shared__ float sz[LL][SCPB];

    {
        const float4* s4 = (const float4*)(dbc + (size_t)b * LL * NDBC);
        float4* d4 = (float4*)&sdbc[0][0];
        for (int i = t; i < LL * NDBC / 4; i += 64) d4[i] = s4[i];
        for (int i = t; i < LL * (SCPB / 4); i += 64) {
            const int l = i >> 4, c = i & 15;
            ((float4*)&su[l][0])[c] =
                ((const float4*)(u + (size_t)(b * LL + l) * DI + di0))[c];
            ((float4*)&sz[l][0])[c] =
                ((const float4*)(xz + (size_t)(b * LL + l) * 2 * DI + DI + di0))[c];
        }
    }

    float wdt[DR], A[DS];
    {
        const float4* w4 = (const float4*)(dtw + (size_t)di * DR);
        #pragma unroll
        for (int q = 0; q < DR / 4; ++q) {
            float4 v = w4[q];
            wdt[q * 4 + 0] = v.x; wdt[q * 4 + 1] = v.y;
            wdt[q * 4 + 2] = v.z; wdt[q * 4 + 3] = v.w;
        }
        const float4* a4 = (const float4*)(A_log + (size_t)di * DS);
        #pragma unroll
        for (int q = 0; q < DS / 4; ++q) {
            float4 v = a4[q];
            A[q * 4 + 0] = -expf(v.x); A[q * 4 + 1] = -expf(v.y);
            A[q * 4 + 2] = -expf(v.z); A[q * 4 + 3] = -expf(v.w);
        }
    }
    const float dbias = dtb[di];
    const float Dd = Dv[di];

    __syncthreads();

    float st_[DS];
    #pragma unroll
    for (int s = 0; s < DS; ++s) st_[s] = 0.f;

    #pragma unroll 4
    for (int l = 0; l < LL; ++l) {
        float dtv = dbias;
        #pragma unroll
        for (int r = 0; r < DR; ++r) dtv += wdt[r] * sdbc[l][r];
        const float d = softplusf_(dtv);

        const float uu = su[l][t];
        const float du = d * uu;
        float yv = 0.f;
        #pragma unroll
        for (int s = 0; s < DS; ++s) {
            st_[s] = __expf(d * A[s]) * st_[s] + du * sdbc[l][DR + s];
            yv += st_[s] * sdbc[l][DR + DS + s];
        }
        yb[(size_t)(b * LL + l) * DI + di] =
            __float2bfloat16((yv + uu * Dd) * siluf_(sz[l][t]));
    }
}

__global__ void pool_classifier_kernel(const float* __restrict__ h,   // [NTOK, DM]
                                       const float* __restrict__ cls, // [NOUT, DM]
                                       float* __restrict__ out) {     // [BB, NOUT]
    const int b = blockIdx.x;
    const int dm = threadIdx.x;
    __shared__ float pool[DM];
    float p = 0.f;
    for (int l = 0; l < LL; ++l) p += h[(size_t)(b * LL + l) * DM + dm];
    pool[dm] = p * (1.0f / LL);
    __syncthreads();
    if (dm < NOUT) {
        float acc = 0.f;
        for (int k = 0; k < DM; ++k) acc += pool[k] * cls[dm * DM + k];
        out[b * NOUT + dm] = acc;
    }
}

extern "C" void kernel_launch(void* const* d_in, const int* in_sizes, int n_in,
                              void* d_out, int out_size, void* d_ws, size_t ws_size,
                              hipStream_t stream) {
    const float* x       = (const float*)d_in[0];
    const float* ipw     = (const float*)d_in[1];
    const float* inw     = (const float*)d_in[2];
    const float* convw   = (const float*)d_in[3];
    const float* convb   = (const float*)d_in[4];
    const float* xpw     = (const float*)d_in[5];
    const float* dtw     = (const float*)d_in[6];
    const float* dtb     = (const float*)d_in[7];
    const float* alog    = (const float*)d_in[8];
    const float* Dvec    = (const float*)d_in[9];
    const float* opw     = (const float*)d_in[10];
    const float* clsw    = (const float*)d_in[11];
    float* out = (float*)d_out;

    // -------- workspace layout (39.7 MB total) --------
    float* h   = (float*)d_ws;                    // 917504
    float* xz  = h + 917504;                      // 3670016
    float* u   = xz + 3670016;                    // 1835008
    float* dbc = u + 1835008;                     // 172032
    __hip_bfloat16* hb   = (__hip_bfloat16*)(dbc + 172032);
    __hip_bfloat16* ub   = hb + 917504;
    __hip_bfloat16* yb   = ub + 1835008;
    __hip_bfloat16* inwb = yb + 1835008;          // 5*1024*256 = 1310720
    __hip_bfloat16* opwb = inwb + 1310720;        // 5*256*512  = 655360
    __hip_bfloat16* xpwb = opwb + 655360;         // 5*48*512   = 122880

    dim3 blk(256);

    // weight casts (all layers at once)
    hipLaunchKernelGGL(cast_f32_bf16, dim3(1310720 / 1024), blk, 0, stream, inw, inwb, 1310720);
    hipLaunchKernelGGL(cast_f32_bf16, dim3(655360 / 1024), blk, 0, stream, opw, opwb, 655360);
    hipLaunchKernelGGL(cast_f32_bf16, dim3(122880 / 1024), blk, 0, stream, xpw, xpwb, 122880);

    // input projection: h = x @ ipw^T   (M=3584, N=256, K=28), fp32
    hipLaunchKernelGGL((gemm_nt<4, 4, 0>), dim3(DM / 64, NTOK / 64), blk, 0, stream,
                       x, FF, ipw, h, NTOK, DM, FF);
    hipLaunchKernelGGL(cast_f32_bf16, dim3(917504 / 1024), blk, 0, stream, h, hb, 917504);

    for (int layer = 0; layer < NLAYER; ++layer) {
        const __hip_bfloat16* inwb_l = inwb + (size_t)layer * 2 * DI * DM;
        const __hip_bfloat16* xpwb_l = xpwb + (size_t)layer * NDBC * DI;
        const __hip_bfloat16* opwb_l = opwb + (size_t)layer * DM * DI;
        const float* convw_l = convw + (size_t)layer * DI * KK;
        const float* convb_l = convb + (size_t)layer * DI;
        const float* dtw_l   = dtw  + (size_t)layer * DI * DR;
        const float* dtb_l   = dtb  + (size_t)layer * DI;
        const float* alog_l  = alog + (size_t)layer * DI * DS;
        const float* Dvec_l  = Dvec + (size_t)layer * DI;

        // xz = h @ inw^T   (M=3584, N=1024, K=256)  MFMA
        hipLaunchKernelGGL((gemm_mfma_nt<64, 64, 2, 2, 0>),
                           dim3(2 * DI / 64, NTOK / 64), blk, 0, stream,
                           hb, DM, inwb_l, xz, (__hip_bfloat16*)nullptr, NTOK, 2 * DI, DM);

        // u = silu(conv(xb) + cb)  (fp32 + bf16 outputs)
        hipLaunchKernelGGL(conv_silu_kernel, dim3((NTOK * DI) / 256), blk, 0, stream,
                           xz, convw_l, convb_l, u, ub);

        // dbc = u @ xpw^T   (M=3584, N=48, K=512)  MFMA
        hipLaunchKernelGGL((gemm_mfma_nt<64, 48, 4, 1, 0>),
                           dim3(1, NTOK / 64), blk, 0, stream,
                           ub, DI, xpwb_l, dbc, (__hip_bfloat16*)nullptr, NTOK, NDBC, DI);

        // selective scan (thread-per-channel; writes y as bf16)
        hipLaunchKernelGGL(scan_kernel, dim3(BB, DI / SCPB), dim3(SCPB), 0, stream,
                           u, dbc, xz, dtw_l, dtb_l, alog_l, Dvec_l, yb);

        // h += y @ opw^T   (M=3584, N=256, K=512)  MFMA, dual-writes h + hb
        hipLaunchKernelGGL((gemm_mfma_nt<64, 64, 2, 2, 2>),
                           dim3(DM / 64, NTOK / 64), blk, 0, stream,
                           yb, DI, opwb_l, h, hb, NTOK, DM, DI);
    }

    hipLaunchKernelGGL(pool_classifier_kernel, dim3(BB), dim3(DM), 0, stream,
                       h, clsw, out);
}

// Round 7
// 324.628 us; speedup vs baseline: 3.4752x; 1.2323x over previous
//
#include <hip/hip_runtime.h>
#include <hip/hip_bf16.h>
#include <cstdint>

#define BB 128
#define LL 28
#define FF 28
#define DM 256
#define DI 512
#define DS 16
#define DR 16
#define KK 3
#define NLAYER 5
#define NOUT 10
#define NTOK (BB * LL)      // 3584
#define NDBC (DR + 2 * DS)  // 48
#define SCH 64              // channels per scan block

typedef __attribute__((ext_vector_type(8))) short bf16x8;
typedef __attribute__((ext_vector_type(4))) float f32x4;

__device__ __forceinline__ float sigmoidf_(float x) { return 1.0f / (1.0f + __expf(-x)); }
__device__ __forceinline__ float siluf_(float x) { return x * sigmoidf_(x); }
__device__ __forceinline__ float softplusf_(float x) {
    return (x > 20.0f) ? x : log1pf(expf(x));
}

// ---------------- fp32 tiled GEMM (input projection only, K=28) ----------------
template <int TM, int TN, int EPI>
__global__ __launch_bounds__(256) void gemm_nt(const float* __restrict__ A, int lda,
                                               const float* __restrict__ W,
                                               float* __restrict__ C,
                                               int M, int N, int K) {
    constexpr int BM = 16 * TM;
    constexpr int BN = 16 * TN;
    __shared__ float As[16][BM + 4];
    __shared__ float Ws[16][BN + 4];

    const int tid = threadIdx.x;
    const int kk = tid & 15;
    const int row = tid >> 4;
    const int tx = tid & 15;
    const int ty = tid >> 4;
    const int bm = blockIdx.y * BM;
    const int bn = blockIdx.x * BN;

    float acc[TM][TN];
    #pragma unroll
    for (int i = 0; i < TM; ++i)
        #pragma unroll
        for (int j = 0; j < TN; ++j) acc[i][j] = 0.f;

    for (int k0 = 0; k0 < K; k0 += 16) {
        const int k = k0 + kk;
        const bool kok = (k < K);
        #pragma unroll
        for (int r = 0; r < TM; ++r) {
            int m = bm + r * 16 + row;
            As[kk][r * 16 + row] = kok ? A[(size_t)m * lda + k] : 0.f;
        }
        #pragma unroll
        for (int r = 0; r < TN; ++r) {
            int n = bn + r * 16 + row;
            Ws[kk][r * 16 + row] = kok ? W[(size_t)n * K + k] : 0.f;
        }
        __syncthreads();
        #pragma unroll
        for (int k2 = 0; k2 < 16; ++k2) {
            float a[TM], b[TN];
            #pragma unroll
            for (int i = 0; i < TM; ++i) a[i] = As[k2][ty * TM + i];
            #pragma unroll
            for (int j = 0; j < TN; ++j) b[j] = Ws[k2][tx * TN + j];
            #pragma unroll
            for (int i = 0; i < TM; ++i)
                #pragma unroll
                for (int j = 0; j < TN; ++j) acc[i][j] += a[i] * b[j];
        }
        __syncthreads();
    }

    #pragma unroll
    for (int i = 0; i < TM; ++i) {
        const int m = bm + ty * TM + i;
        #pragma unroll
        for (int j = 0; j < TN; ++j) {
            const int n = bn + tx * TN + j;
            float v = acc[i][j];
            if (EPI == 2) v += C[(size_t)m * N + n];
            C[(size_t)m * N + n] = v;
        }
    }
}

// ---------------- bf16 MFMA GEMM: C[M,N] (+)= A[M,K] @ W[N,K]^T ----------------
template <int BM, int BN, int WAVES_M, int WAVES_N, int EPI>
__global__ __launch_bounds__(256) void gemm_mfma_nt(
        const __hip_bfloat16* __restrict__ A, int lda,
        const __hip_bfloat16* __restrict__ W,   // [N][K]
        float* __restrict__ C,
        __hip_bfloat16* __restrict__ Cb,
        int M, int N, int K) {
    constexpr int BK = 32;
    constexpr int LDT = BK + 8;
    constexpr int WTM = BM / WAVES_M;
    constexpr int WTN = BN / WAVES_N;
    constexpr int FM = WTM / 16;
    constexpr int FN = WTN / 16;

    __shared__ __align__(16) __hip_bfloat16 As[BM][LDT];
    __shared__ __align__(16) __hip_bfloat16 Ws[BN][LDT];

    const int tid = threadIdx.x;
    const int wave = tid >> 6;
    const int lane = tid & 63;
    const int wr = wave / WAVES_N;
    const int wc = wave % WAVES_N;
    const int bm = blockIdx.y * BM;
    const int bn = blockIdx.x * BN;

    const int r4 = tid >> 2;
    const int c8 = (tid & 3) * 8;

    f32x4 acc[FM][FN] = {};

    const int koff = (lane >> 4) * 8;
    const int rla = lane & 15;

    for (int k0 = 0; k0 < K; k0 += BK) {
        for (int rr = r4; rr < BM; rr += 64)
            *(int4*)&As[rr][c8] = *(const int4*)&A[(size_t)(bm + rr) * lda + k0 + c8];
        for (int rr = r4; rr < BN; rr += 64)
            *(int4*)&Ws[rr][c8] = *(const int4*)&W[(size_t)(bn + rr) * K + k0 + c8];
        __syncthreads();

        bf16x8 af[FM], wf[FN];
        #pragma unroll
        for (int i = 0; i < FM; ++i)
            af[i] = *(const bf16x8*)&As[wr * WTM + i * 16 + rla][koff];
        #pragma unroll
        for (int j = 0; j < FN; ++j)
            wf[j] = *(const bf16x8*)&Ws[wc * WTN + j * 16 + rla][koff];
        #pragma unroll
        for (int i = 0; i < FM; ++i)
            #pragma unroll
            for (int j = 0; j < FN; ++j)
                acc[i][j] = __builtin_amdgcn_mfma_f32_16x16x32_bf16(af[i], wf[j], acc[i][j], 0, 0, 0);
        __syncthreads();
    }

    const int lrow = (lane >> 4) * 4;
    const int lcol = lane & 15;
    #pragma unroll
    for (int i = 0; i < FM; ++i) {
        #pragma unroll
        for (int j = 0; j < FN; ++j) {
            #pragma unroll
            for (int r = 0; r < 4; ++r) {
                const int m = bm + wr * WTM + i * 16 + lrow + r;
                const int n = bn + wc * WTN + j * 16 + lcol;
                float v = acc[i][j][r];
                if (EPI == 2) {
                    v += C[(size_t)m * N + n];
                    C[(size_t)m * N + n] = v;
                    Cb[(size_t)m * N + n] = __float2bfloat16(v);
                } else {
                    C[(size_t)m * N + n] = v;
                }
            }
        }
    }
}

// ---------------- elementwise cast fp32 -> bf16 ----------------
__global__ void cast_f32_bf16(const float* __restrict__ s, __hip_bfloat16* __restrict__ d, int n) {
    int i = (blockIdx.x * 256 + threadIdx.x) * 4;
    if (i >= n) return;
    float4 v = *(const float4*)&s[i];
    d[i + 0] = __float2bfloat16(v.x);
    d[i + 1] = __float2bfloat16(v.y);
    d[i + 2] = __float2bfloat16(v.z);
    d[i + 3] = __float2bfloat16(v.w);
}

// u = silu(conv(xb)+cb), written fp32 (for scan) and bf16 (for x_proj GEMM)
__global__ void conv_silu_kernel(const float* __restrict__ xz,
                                 const float* __restrict__ cw,   // [DI, K]
                                 const float* __restrict__ cb,   // [DI]
                                 float* __restrict__ u,
                                 __hip_bfloat16* __restrict__ ub) {
    int idx = blockIdx.x * 256 + threadIdx.x;
    if (idx >= NTOK * DI) return;
    int di = idx & (DI - 1);
    int m = idx >> 9;
    int l = m % LL;
    int b = m / LL;
    float acc = cb[di];
    #pragma unroll
    for (int k = 0; k < KK; ++k) {
        int lsrc = l + k - (KK - 1);
        if (lsrc >= 0) {
            acc += xz[(size_t)(b * LL + lsrc) * (2 * DI) + di] * cw[di * KK + k];
        }
    }
    float v = siluf_(acc);
    u[(size_t)m * DI + di] = v;
    ub[(size_t)m * DI + di] = __float2bfloat16(v);
}

// ---------------- selective scan, 4-threads-per-channel ----------------
// Block: 256 threads = 4 waves; covers 64 channels of one batch element.
// Grid: (BB, DI/64) = 1024 blocks -> 4096 waves = 4 waves/SIMD.
// Phase 1 (parallel): stage dbc/u/silu(z); compute delta[l][ch] =
//   softplus(dt . dtw_row + dtb) with one thread per (l,ch) output.
// Phase 2 (scan): thread = (ch, state-quad); 4 register states; per step:
//   4x{mul,exp,fma,fma} + 2-shuffle 4-lane reduce. No barriers, no chains >4.
__global__ __launch_bounds__(256) void scan_kernel(
                            const float* __restrict__ u,     // [NTOK, DI]
                            const float* __restrict__ dbc,   // [NTOK, NDBC]
                            const float* __restrict__ xz,    // [NTOK, 2*DI]
                            const float* __restrict__ dtw,   // [DI, DR]
                            const float* __restrict__ dtb,   // [DI]
                            const float* __restrict__ A_log, // [DI, DS]
                            const float* __restrict__ Dv,    // [DI]
                            __hip_bfloat16* __restrict__ yb) { // [NTOK, DI]
    const int b = blockIdx.x;
    const int di0 = blockIdx.y * SCH;
    const int t = threadIdx.x;
    const int wave = t >> 6;
    const int lane = t & 63;

    __shared__ float sdbc[LL][NDBC];   // 5.25 KB  dt|B|C rows
    __shared__ float su[LL][SCH];      // 7 KB     u
    __shared__ float sgz[LL][SCH];     // 7 KB     silu(z)
    __shared__ float sdelta[LL][SCH];  // 7 KB     softplus(dt_proj)
    __shared__ float sD[SCH];          // 256 B

    // ---- stage dbc rows (float4) ----
    {
        const float4* s4 = (const float4*)(dbc + (size_t)b * LL * NDBC);
        float4* d4 = (float4*)&sdbc[0][0];
        for (int i = t; i < LL * NDBC / 4; i += 256) d4[i] = s4[i];
    }
    // ---- stage u and silu(z) (float4) ----
    for (int i = t; i < LL * (SCH / 4); i += 256) {
        const int l = i >> 4, c4 = (i & 15) * 4;
        float4 uv = *(const float4*)(u + (size_t)(b * LL + l) * DI + di0 + c4);
        *(float4*)&su[l][c4] = uv;
        float4 zv = *(const float4*)(xz + (size_t)(b * LL + l) * 2 * DI + DI + di0 + c4);
        float4 gv;
        gv.x = siluf_(zv.x); gv.y = siluf_(zv.y);
        gv.z = siluf_(zv.z); gv.w = siluf_(zv.w);
        *(float4*)&sgz[l][c4] = gv;
    }
    if (t < SCH) sD[t] = Dv[di0 + t];

    // per-thread dtw row for the delta phase (channel = lane)
    float wrow[DR];
    {
        const float4* w4 = (const float4*)(dtw + (size_t)(di0 + lane) * DR);
        #pragma unroll
        for (int q = 0; q < DR / 4; ++q) {
            float4 v = w4[q];
            wrow[q * 4 + 0] = v.x; wrow[q * 4 + 1] = v.y;
            wrow[q * 4 + 2] = v.z; wrow[q * 4 + 3] = v.w;
        }
    }
    const float dbias = dtb[di0 + lane];

    __syncthreads();

    // ---- phase 1: delta[l][ch], one (l,ch) per thread, 7 per thread ----
    #pragma unroll
    for (int j = 0; j < 7; ++j) {
        const int l = wave + j * 4;
        float dtv = dbias;
        #pragma unroll
        for (int r = 0; r < DR; ++r) dtv += wrow[r] * sdbc[l][r];
        sdelta[l][lane] = softplusf_(dtv);
    }

    // ---- scan-phase constants: thread = (ch, state-quad) ----
    const int ch = t >> 2;      // 0..63
    const int sq = t & 3;       // state quad
    const int di = di0 + ch;
    float A0, A1, A2, A3;
    {
        float4 av = *(const float4*)(A_log + (size_t)di * DS + sq * 4);
        A0 = -__expf(av.x); A1 = -__expf(av.y);
        A2 = -__expf(av.z); A3 = -__expf(av.w);
    }

    __syncthreads();

    const float Dd = sD[ch];
    float st0 = 0.f, st1 = 0.f, st2 = 0.f, st3 = 0.f;

    #pragma unroll
    for (int l = 0; l < LL; ++l) {
        const float d  = sdelta[l][ch];
        const float uu = su[l][ch];
        const float du = d * uu;
        const float4 Bv = *(const float4*)&sdbc[l][DR + sq * 4];
        const float4 Cv = *(const float4*)&sdbc[l][DR + DS + sq * 4];
        st0 = __expf(d * A0) * st0 + du * Bv.x;
        st1 = __expf(d * A1) * st1 + du * Bv.y;
        st2 = __expf(d * A2) * st2 + du * Bv.z;
        st3 = __expf(d * A3) * st3 + du * Bv.w;
        float p = st0 * Cv.x + st1 * Cv.y + st2 * Cv.z + st3 * Cv.w;
        p += __shfl_xor(p, 1);
        p += __shfl_xor(p, 2);
        if (sq == 0)
            yb[(size_t)(b * LL + l) * DI + di] =
                __float2bfloat16((p + uu * Dd) * sgz[l][ch]);
    }
}

__global__ void pool_classifier_kernel(const float* __restrict__ h,   // [NTOK, DM]
                                       const float* __restrict__ cls, // [NOUT, DM]
                                       float* __restrict__ out) {     // [BB, NOUT]
    const int b = blockIdx.x;
    const int dm = threadIdx.x;
    __shared__ float pool[DM];
    float p = 0.f;
    for (int l = 0; l < LL; ++l) p += h[(size_t)(b * LL + l) * DM + dm];
    pool[dm] = p * (1.0f / LL);
    __syncthreads();
    if (dm < NOUT) {
        float acc = 0.f;
        for (int k = 0; k < DM; ++k) acc += pool[k] * cls[dm * DM + k];
        out[b * NOUT + dm] = acc;
    }
}

extern "C" void kernel_launch(void* const* d_in, const int* in_sizes, int n_in,
                              void* d_out, int out_size, void* d_ws, size_t ws_size,
                              hipStream_t stream) {
    const float* x       = (const float*)d_in[0];
    const float* ipw     = (const float*)d_in[1];
    const float* inw     = (const float*)d_in[2];
    const float* convw   = (const float*)d_in[3];
    const float* convb   = (const float*)d_in[4];
    const float* xpw     = (const float*)d_in[5];
    const float* dtw     = (const float*)d_in[6];
    const float* dtb     = (const float*)d_in[7];
    const float* alog    = (const float*)d_in[8];
    const float* Dvec    = (const float*)d_in[9];
    const float* opw     = (const float*)d_in[10];
    const float* clsw    = (const float*)d_in[11];
    float* out = (float*)d_out;

    // -------- workspace layout --------
    float* h   = (float*)d_ws;                    // 917504
    float* xz  = h + 917504;                      // 3670016
    float* u   = xz + 3670016;                    // 1835008
    float* dbc = u + 1835008;                     // 172032
    __hip_bfloat16* hb   = (__hip_bfloat16*)(dbc + 172032);
    __hip_bfloat16* ub   = hb + 917504;
    __hip_bfloat16* yb   = ub + 1835008;
    __hip_bfloat16* inwb = yb + 1835008;          // 5*1024*256
    __hip_bfloat16* opwb = inwb + 1310720;        // 5*256*512
    __hip_bfloat16* xpwb = opwb + 655360;         // 5*48*512

    dim3 blk(256);

    // weight casts (all layers at once)
    hipLaunchKernelGGL(cast_f32_bf16, dim3(1310720 / 1024), blk, 0, stream, inw, inwb, 1310720);
    hipLaunchKernelGGL(cast_f32_bf16, dim3(655360 / 1024), blk, 0, stream, opw, opwb, 655360);
    hipLaunchKernelGGL(cast_f32_bf16, dim3(122880 / 1024), blk, 0, stream, xpw, xpwb, 122880);

    // input projection: h = x @ ipw^T   (M=3584, N=256, K=28), fp32
    hipLaunchKernelGGL((gemm_nt<4, 4, 0>), dim3(DM / 64, NTOK / 64), blk, 0, stream,
                       x, FF, ipw, h, NTOK, DM, FF);
    hipLaunchKernelGGL(cast_f32_bf16, dim3(917504 / 1024), blk, 0, stream, h, hb, 917504);

    for (int layer = 0; layer < NLAYER; ++layer) {
        const __hip_bfloat16* inwb_l = inwb + (size_t)layer * 2 * DI * DM;
        const __hip_bfloat16* xpwb_l = xpwb + (size_t)layer * NDBC * DI;
        const __hip_bfloat16* opwb_l = opwb + (size_t)layer * DM * DI;
        const float* convw_l = convw + (size_t)layer * DI * KK;
        const float* convb_l = convb + (size_t)layer * DI;
        const float* dtw_l   = dtw  + (size_t)layer * DI * DR;
        const float* dtb_l   = dtb  + (size_t)layer * DI;
        const float* alog_l  = alog + (size_t)layer * DI * DS;
        const float* Dvec_l  = Dvec + (size_t)layer * DI;

        // xz = h @ inw^T   (M=3584, N=1024, K=256)  MFMA
        hipLaunchKernelGGL((gemm_mfma_nt<64, 64, 2, 2, 0>),
                           dim3(2 * DI / 64, NTOK / 64), blk, 0, stream,
                           hb, DM, inwb_l, xz, (__hip_bfloat16*)nullptr, NTOK, 2 * DI, DM);

        // u = silu(conv(xb) + cb)  (fp32 + bf16 outputs)
        hipLaunchKernelGGL(conv_silu_kernel, dim3((NTOK * DI) / 256), blk, 0, stream,
                           xz, convw_l, convb_l, u, ub);

        // dbc = u @ xpw^T   (M=3584, N=48, K=512)  MFMA
        hipLaunchKernelGGL((gemm_mfma_nt<64, 48, 4, 1, 0>),
                           dim3(1, NTOK / 64), blk, 0, stream,
                           ub, DI, xpwb_l, dbc, (__hip_bfloat16*)nullptr, NTOK, NDBC, DI);

        // selective scan (4-threads-per-channel, fused dt_proj + gating)
        hipLaunchKernelGGL(scan_kernel, dim3(BB, DI / SCH), blk, 0, stream,
                           u, dbc, xz, dtw_l, dtb_l, alog_l, Dvec_l, yb);

        // h += y @ opw^T   (M=3584, N=256, K=512)  MFMA, dual-writes h + hb
        hipLaunchKernelGGL((gemm_mfma_nt<64, 64, 2, 2, 2>),
                           dim3(DM / 64, NTOK / 64), blk, 0, stream,
                           yb, DI, opwb_l, h, hb, NTOK, DM, DI);
    }

    hipLaunchKernelGGL(pool_classifier_kernel, dim3(BB), dim3(DM), 0, stream,
                       h, clsw, out);
}

// Round 8
// 318.124 us; speedup vs baseline: 3.5463x; 1.0204x over previous
//
#include <hip/hip_runtime.h>
#include <hip/hip_bf16.h>
#include <cstdint>

#define BB 128
#define LL 28
#define FF 28
#define DM 256
#define DI 512
#define DS 16
#define DR 16
#define KK 3
#define NLAYER 5
#define NOUT 10
#define NTOK (BB * LL)      // 3584
#define NDBC (DR + 2 * DS)  // 48
#define SCH 64              // channels per scan block

typedef __attribute__((ext_vector_type(8))) short bf16x8;
typedef __attribute__((ext_vector_type(4))) float f32x4;

__device__ __forceinline__ float sigmoidf_(float x) { return 1.0f / (1.0f + __expf(-x)); }
__device__ __forceinline__ float siluf_(float x) { return x * sigmoidf_(x); }
__device__ __forceinline__ float softplusf_(float x) {
    return (x > 20.0f) ? x : log1pf(expf(x));
}

// ---------------- fp32 tiled GEMM body (input projection, K=28) ----------------
// EPI 0: C = AB      EPI 3: C = AB and Cb = bf16(AB)
template <int TM, int TN, int EPI>
__device__ __forceinline__ void gemm_nt_body(const float* __restrict__ A, int lda,
                                             const float* __restrict__ W,
                                             float* __restrict__ C,
                                             __hip_bfloat16* __restrict__ Cb,
                                             int M, int N, int K) {
    constexpr int BM = 16 * TM;
    constexpr int BN = 16 * TN;
    __shared__ float As[16][BM + 4];
    __shared__ float Ws[16][BN + 4];

    const int tid = threadIdx.x;
    const int kk = tid & 15;
    const int row = tid >> 4;
    const int tx = tid & 15;
    const int ty = tid >> 4;
    const int bm = blockIdx.y * BM;
    const int bn = blockIdx.x * BN;

    float acc[TM][TN];
    #pragma unroll
    for (int i = 0; i < TM; ++i)
        #pragma unroll
        for (int j = 0; j < TN; ++j) acc[i][j] = 0.f;

    for (int k0 = 0; k0 < K; k0 += 16) {
        const int k = k0 + kk;
        const bool kok = (k < K);
        #pragma unroll
        for (int r = 0; r < TM; ++r) {
            int m = bm + r * 16 + row;
            As[kk][r * 16 + row] = kok ? A[(size_t)m * lda + k] : 0.f;
        }
        #pragma unroll
        for (int r = 0; r < TN; ++r) {
            int n = bn + r * 16 + row;
            Ws[kk][r * 16 + row] = kok ? W[(size_t)n * K + k] : 0.f;
        }
        __syncthreads();
        #pragma unroll
        for (int k2 = 0; k2 < 16; ++k2) {
            float a[TM], b[TN];
            #pragma unroll
            for (int i = 0; i < TM; ++i) a[i] = As[k2][ty * TM + i];
            #pragma unroll
            for (int j = 0; j < TN; ++j) b[j] = Ws[k2][tx * TN + j];
            #pragma unroll
            for (int i = 0; i < TM; ++i)
                #pragma unroll
                for (int j = 0; j < TN; ++j) acc[i][j] += a[i] * b[j];
        }
        __syncthreads();
    }

    #pragma unroll
    for (int i = 0; i < TM; ++i) {
        const int m = bm + ty * TM + i;
        #pragma unroll
        for (int j = 0; j < TN; ++j) {
            const int n = bn + tx * TN + j;
            float v = acc[i][j];
            C[(size_t)m * N + n] = v;
            if (EPI == 3) Cb[(size_t)m * N + n] = __float2bfloat16(v);
        }
    }
}

// ---------------- bf16 MFMA GEMM body: C[M,N] (+)= A[M,K] @ W[N,K]^T ----------------
// EPI 0: C = acc.  EPI 2: C += acc, Cb = bf16(C_new) mirror.
template <int BM, int BN, int WAVES_M, int WAVES_N, int EPI>
__device__ __forceinline__ void gemm_mfma_body(
        const __hip_bfloat16* __restrict__ A, int lda,
        const __hip_bfloat16* __restrict__ W,   // [N][K]
        float* __restrict__ C,
        __hip_bfloat16* __restrict__ Cb,
        int M, int N, int K) {
    constexpr int BK = 32;
    constexpr int LDT = BK + 8;
    constexpr int WTM = BM / WAVES_M;
    constexpr int WTN = BN / WAVES_N;
    constexpr int FM = WTM / 16;
    constexpr int FN = WTN / 16;

    __shared__ __align__(16) __hip_bfloat16 As[BM][LDT];
    __shared__ __align__(16) __hip_bfloat16 Ws[BN][LDT];

    const int tid = threadIdx.x;
    const int wave = tid >> 6;
    const int lane = tid & 63;
    const int wr = wave / WAVES_N;
    const int wc = wave % WAVES_N;
    const int bm = blockIdx.y * BM;
    const int bn = blockIdx.x * BN;

    const int r4 = tid >> 2;
    const int c8 = (tid & 3) * 8;

    f32x4 acc[FM][FN] = {};

    const int koff = (lane >> 4) * 8;
    const int rla = lane & 15;

    for (int k0 = 0; k0 < K; k0 += BK) {
        for (int rr = r4; rr < BM; rr += 64)
            *(int4*)&As[rr][c8] = *(const int4*)&A[(size_t)(bm + rr) * lda + k0 + c8];
        for (int rr = r4; rr < BN; rr += 64)
            *(int4*)&Ws[rr][c8] = *(const int4*)&W[(size_t)(bn + rr) * K + k0 + c8];
        __syncthreads();

        bf16x8 af[FM], wf[FN];
        #pragma unroll
        for (int i = 0; i < FM; ++i)
            af[i] = *(const bf16x8*)&As[wr * WTM + i * 16 + rla][koff];
        #pragma unroll
        for (int j = 0; j < FN; ++j)
            wf[j] = *(const bf16x8*)&Ws[wc * WTN + j * 16 + rla][koff];
        #pragma unroll
        for (int i = 0; i < FM; ++i)
            #pragma unroll
            for (int j = 0; j < FN; ++j)
                acc[i][j] = __builtin_amdgcn_mfma_f32_16x16x32_bf16(af[i], wf[j], acc[i][j], 0, 0, 0);
        __syncthreads();
    }

    const int lrow = (lane >> 4) * 4;
    const int lcol = lane & 15;
    #pragma unroll
    for (int i = 0; i < FM; ++i) {
        #pragma unroll
        for (int j = 0; j < FN; ++j) {
            #pragma unroll
            for (int r = 0; r < 4; ++r) {
                const int m = bm + wr * WTM + i * 16 + lrow + r;
                const int n = bn + wc * WTN + j * 16 + lcol;
                float v = acc[i][j][r];
                if (EPI == 2) {
                    v += C[(size_t)m * N + n];
                    C[(size_t)m * N + n] = v;
                    Cb[(size_t)m * N + n] = __float2bfloat16(v);
                } else {
                    C[(size_t)m * N + n] = v;
                }
            }
        }
    }
}

// ---- distinctly-named kernel entry points (for rocprof visibility) ----
__global__ __launch_bounds__(256) void g_inputproj_f32(
        const float* __restrict__ A, int lda, const float* __restrict__ W,
        float* __restrict__ C, __hip_bfloat16* __restrict__ Cb, int M, int N, int K) {
    gemm_nt_body<4, 4, 3>(A, lda, W, C, Cb, M, N, K);
}
__global__ __launch_bounds__(256) void g_xz_mfma(
        const __hip_bfloat16* __restrict__ A, int lda, const __hip_bfloat16* __restrict__ W,
        float* __restrict__ C, __hip_bfloat16* __restrict__ Cb, int M, int N, int K) {
    gemm_mfma_body<64, 64, 2, 2, 0>(A, lda, W, C, Cb, M, N, K);
}
__global__ __launch_bounds__(256) void g_xproj_mfma(
        const __hip_bfloat16* __restrict__ A, int lda, const __hip_bfloat16* __restrict__ W,
        float* __restrict__ C, __hip_bfloat16* __restrict__ Cb, int M, int N, int K) {
    gemm_mfma_body<64, 48, 4, 1, 0>(A, lda, W, C, Cb, M, N, K);
}
__global__ __launch_bounds__(256) void g_outproj_mfma(
        const __hip_bfloat16* __restrict__ A, int lda, const __hip_bfloat16* __restrict__ W,
        float* __restrict__ C, __hip_bfloat16* __restrict__ Cb, int M, int N, int K) {
    gemm_mfma_body<64, 64, 2, 2, 2>(A, lda, W, C, Cb, M, N, K);
}

// ---------------- all weight casts in one kernel ----------------
#define N_INW (NLAYER * 2 * DI * DM)   // 1310720
#define N_OPW (NLAYER * DM * DI)       // 655360
#define N_XPW (NLAYER * NDBC * DI)     // 122880
__global__ void cast_weights(const float* __restrict__ inw, const float* __restrict__ opw,
                             const float* __restrict__ xpw,
                             __hip_bfloat16* __restrict__ inwb, __hip_bfloat16* __restrict__ opwb,
                             __hip_bfloat16* __restrict__ xpwb) {
    int i = (blockIdx.x * 256 + threadIdx.x) * 4;
    const float* s; __hip_bfloat16* d; int off;
    if (i < N_INW) { s = inw; d = inwb; off = i; }
    else if (i < N_INW + N_OPW) { s = opw; d = opwb; off = i - N_INW; }
    else if (i < N_INW + N_OPW + N_XPW) { s = xpw; d = xpwb; off = i - N_INW - N_OPW; }
    else return;
    float4 v = *(const float4*)&s[off];
    d[off + 0] = __float2bfloat16(v.x);
    d[off + 1] = __float2bfloat16(v.y);
    d[off + 2] = __float2bfloat16(v.z);
    d[off + 3] = __float2bfloat16(v.w);
}

// u = silu(conv(xb)+cb), written fp32 (for scan) and bf16 (for x_proj GEMM)
__global__ void conv_silu_kernel(const float* __restrict__ xz,
                                 const float* __restrict__ cw,   // [DI, K]
                                 const float* __restrict__ cb,   // [DI]
                                 float* __restrict__ u,
                                 __hip_bfloat16* __restrict__ ub) {
    int idx = blockIdx.x * 256 + threadIdx.x;
    if (idx >= NTOK * DI) return;
    int di = idx & (DI - 1);
    int m = idx >> 9;
    int l = m % LL;
    int b = m / LL;
    float acc = cb[di];
    #pragma unroll
    for (int k = 0; k < KK; ++k) {
        int lsrc = l + k - (KK - 1);
        if (lsrc >= 0) {
            acc += xz[(size_t)(b * LL + lsrc) * (2 * DI) + di] * cw[di * KK + k];
        }
    }
    float v = siluf_(acc);
    u[(size_t)m * DI + di] = v;
    ub[(size_t)m * DI + di] = __float2bfloat16(v);
}

// ---------------- selective scan, 4-threads-per-channel ----------------
// Block: 256 threads = 4 waves; 64 channels of one batch. Grid (BB, DI/64).
// Phase 1: stage + delta[l][ch] (one (l,ch) per thread).
// Phase 2: thread = (ch, state-quad), 4 scalar register states; unroll capped
// at 2 to keep the compiler from hoisting 28 iterations of LDS loads (VGPR).
__global__ __launch_bounds__(256) void scan_kernel(
                            const float* __restrict__ u,     // [NTOK, DI]
                            const float* __restrict__ dbc,   // [NTOK, NDBC]
                            const float* __restrict__ xz,    // [NTOK, 2*DI]
                            const float* __restrict__ dtw,   // [DI, DR]
                            const float* __restrict__ dtb,   // [DI]
                            const float* __restrict__ A_log, // [DI, DS]
                            const float* __restrict__ Dv,    // [DI]
                            __hip_bfloat16* __restrict__ yb) { // [NTOK, DI]
    const int b = blockIdx.x;
    const int di0 = blockIdx.y * SCH;
    const int t = threadIdx.x;
    const int wave = t >> 6;
    const int lane = t & 63;

    __shared__ float sdbc[LL][NDBC];   // 5.25 KB
    __shared__ float su[LL][SCH];      // 7 KB
    __shared__ float sgz[LL][SCH];     // 7 KB
    __shared__ float sdelta[LL][SCH];  // 7 KB
    __shared__ float sD[SCH];

    {
        const float4* s4 = (const float4*)(dbc + (size_t)b * LL * NDBC);
        float4* d4 = (float4*)&sdbc[0][0];
        for (int i = t; i < LL * NDBC / 4; i += 256) d4[i] = s4[i];
    }
    for (int i = t; i < LL * (SCH / 4); i += 256) {
        const int l = i >> 4, c4 = (i & 15) * 4;
        float4 uv = *(const float4*)(u + (size_t)(b * LL + l) * DI + di0 + c4);
        *(float4*)&su[l][c4] = uv;
        float4 zv = *(const float4*)(xz + (size_t)(b * LL + l) * 2 * DI + DI + di0 + c4);
        float4 gv;
        gv.x = siluf_(zv.x); gv.y = siluf_(zv.y);
        gv.z = siluf_(zv.z); gv.w = siluf_(zv.w);
        *(float4*)&sgz[l][c4] = gv;
    }
    if (t < SCH) sD[t] = Dv[di0 + t];

    float wrow[DR];
    {
        const float4* w4 = (const float4*)(dtw + (size_t)(di0 + lane) * DR);
        #pragma unroll
        for (int q = 0; q < DR / 4; ++q) {
            float4 v = w4[q];
            wrow[q * 4 + 0] = v.x; wrow[q * 4 + 1] = v.y;
            wrow[q * 4 + 2] = v.z; wrow[q * 4 + 3] = v.w;
        }
    }
    const float dbias = dtb[di0 + lane];

    __syncthreads();

    #pragma unroll
    for (int j = 0; j < 7; ++j) {
        const int l = wave + j * 4;
        float dtv = dbias;
        #pragma unroll
        for (int r = 0; r < DR; ++r) dtv += wrow[r] * sdbc[l][r];
        sdelta[l][lane] = softplusf_(dtv);
    }

    const int ch = t >> 2;
    const int sq = t & 3;
    const int di = di0 + ch;
    float A0, A1, A2, A3;
    {
        float4 av = *(const float4*)(A_log + (size_t)di * DS + sq * 4);
        A0 = -__expf(av.x); A1 = -__expf(av.y);
        A2 = -__expf(av.z); A3 = -__expf(av.w);
    }

    __syncthreads();

    const float Dd = sD[ch];
    float st0 = 0.f, st1 = 0.f, st2 = 0.f, st3 = 0.f;

    #pragma unroll 2
    for (int l = 0; l < LL; ++l) {
        const float d  = sdelta[l][ch];
        const float uu = su[l][ch];
        const float du = d * uu;
        const float4 Bv = *(const float4*)&sdbc[l][DR + sq * 4];
        const float4 Cv = *(const float4*)&sdbc[l][DR + DS + sq * 4];
        st0 = __expf(d * A0) * st0 + du * Bv.x;
        st1 = __expf(d * A1) * st1 + du * Bv.y;
        st2 = __expf(d * A2) * st2 + du * Bv.z;
        st3 = __expf(d * A3) * st3 + du * Bv.w;
        float p = st0 * Cv.x + st1 * Cv.y + st2 * Cv.z + st3 * Cv.w;
        p += __shfl_xor(p, 1);
        p += __shfl_xor(p, 2);
        if (sq == 0)
            yb[(size_t)(b * LL + l) * DI + di] =
                __float2bfloat16((p + uu * Dd) * sgz[l][ch]);
    }
}

__global__ void pool_classifier_kernel(const float* __restrict__ h,   // [NTOK, DM]
                                       const float* __restrict__ cls, // [NOUT, DM]
                                       float* __restrict__ out) {     // [BB, NOUT]
    const int b = blockIdx.x;
    const int dm = threadIdx.x;
    __shared__ float pool[DM];
    float p = 0.f;
    for (int l = 0; l < LL; ++l) p += h[(size_t)(b * LL + l) * DM + dm];
    pool[dm] = p * (1.0f / LL);
    __syncthreads();
    if (dm < NOUT) {
        float acc = 0.f;
        for (int k = 0; k < DM; ++k) acc += pool[k] * cls[dm * DM + k];
        out[b * NOUT + dm] = acc;
    }
}

extern "C" void kernel_launch(void* const* d_in, const int* in_sizes, int n_in,
                              void* d_out, int out_size, void* d_ws, size_t ws_size,
                              hipStream_t stream) {
    const float* x       = (const float*)d_in[0];
    const float* ipw     = (const float*)d_in[1];
    const float* inw     = (const float*)d_in[2];
    const float* convw   = (const float*)d_in[3];
    const float* convb   = (const float*)d_in[4];
    const float* xpw     = (const float*)d_in[5];
    const float* dtw     = (const float*)d_in[6];
    const float* dtb     = (const float*)d_in[7];
    const float* alog    = (const float*)d_in[8];
    const float* Dvec    = (const float*)d_in[9];
    const float* opw     = (const float*)d_in[10];
    const float* clsw    = (const float*)d_in[11];
    float* out = (float*)d_out;

    // -------- workspace layout --------
    float* h   = (float*)d_ws;                    // 917504
    float* xz  = h + 917504;                      // 3670016
    float* u   = xz + 3670016;                    // 1835008
    float* dbc = u + 1835008;                     // 172032
    __hip_bfloat16* hb   = (__hip_bfloat16*)(dbc + 172032);
    __hip_bfloat16* ub   = hb + 917504;
    __hip_bfloat16* yb   = ub + 1835008;
    __hip_bfloat16* inwb = yb + 1835008;          // N_INW
    __hip_bfloat16* opwb = inwb + N_INW;          // N_OPW
    __hip_bfloat16* xpwb = opwb + N_OPW;          // N_XPW

    dim3 blk(256);

    // one fused weight-cast kernel (2088960 floats / 4 per thread)
    hipLaunchKernelGGL(cast_weights, dim3((N_INW + N_OPW + N_XPW) / 1024), blk, 0, stream,
                       inw, opw, xpw, inwb, opwb, xpwb);

    // input projection: h = x @ ipw^T (M=3584,N=256,K=28), dual-writes h + hb
    hipLaunchKernelGGL(g_inputproj_f32, dim3(DM / 64, NTOK / 64), blk, 0, stream,
                       x, FF, ipw, h, hb, NTOK, DM, FF);

    for (int layer = 0; layer < NLAYER; ++layer) {
        const __hip_bfloat16* inwb_l = inwb + (size_t)layer * 2 * DI * DM;
        const __hip_bfloat16* xpwb_l = xpwb + (size_t)layer * NDBC * DI;
        const __hip_bfloat16* opwb_l = opwb + (size_t)layer * DM * DI;
        const float* convw_l = convw + (size_t)layer * DI * KK;
        const float* convb_l = convb + (size_t)layer * DI;
        const float* dtw_l   = dtw  + (size_t)layer * DI * DR;
        const float* dtb_l   = dtb  + (size_t)layer * DI;
        const float* alog_l  = alog + (size_t)layer * DI * DS;
        const float* Dvec_l  = Dvec + (size_t)layer * DI;

        // xz = h @ inw^T   (M=3584, N=1024, K=256)  MFMA
        hipLaunchKernelGGL(g_xz_mfma, dim3(2 * DI / 64, NTOK / 64), blk, 0, stream,
                           hb, DM, inwb_l, xz, (__hip_bfloat16*)nullptr, NTOK, 2 * DI, DM);

        // u = silu(conv(xb) + cb)
        hipLaunchKernelGGL(conv_silu_kernel, dim3((NTOK * DI) / 256), blk, 0, stream,
                           xz, convw_l, convb_l, u, ub);

        // dbc = u @ xpw^T   (M=3584, N=48, K=512)  MFMA
        hipLaunchKernelGGL(g_xproj_mfma, dim3(1, NTOK / 64), blk, 0, stream,
                           ub, DI, xpwb_l, dbc, (__hip_bfloat16*)nullptr, NTOK, NDBC, DI);

        // selective scan (4-threads-per-channel, fused dt_proj + gating)
        hipLaunchKernelGGL(scan_kernel, dim3(BB, DI / SCH), blk, 0, stream,
                           u, dbc, xz, dtw_l, dtb_l, alog_l, Dvec_l, yb);

        // h += y @ opw^T   (M=3584, N=256, K=512)  MFMA, dual-writes h + hb
        hipLaunchKernelGGL(g_outproj_mfma, dim3(DM / 64, NTOK / 64), blk, 0, stream,
                           yb, DI, opwb_l, h, hb, NTOK, DM, DI);
    }

    hipLaunchKernelGGL(pool_classifier_kernel, dim3(BB), dim3(DM), 0, stream,
                       h, clsw, out);
}